// Round 8
// baseline (338.604 us; speedup 1.0000x reference)
//
#include <hip/hip_runtime.h>

// SSIM 3D loss: pred/target f32 [4,1,64,192,192], scalar 1 - mean(ssim_map).
// v7: SINGLE fused kernel. Block = 16x16 (h,w) tile x batch x D-segment,
//     marching along D. Per plane: stage 26x26 halo -> W-blur (fp16-pair
//     packed) -> H-blur -> 11-plane LDS ring of 5 blurred fields
//     (4 fields packed h8 + pt u16). Ring full => per-pixel D-dot + SSIM,
//     accumulated in registers. No field volumes in global memory at all.
//     D-head via ring zero-init; D-tail via virtual zero planes (dd 64..68).
//     finalize sums 1152 block partials.

#define D_DIM 64
#define H_DIM 192
#define W_DIM 192
#define SLICE (H_DIM * W_DIM)   // 36864
#define VOL   (D_DIM * SLICE)   // 2359296
#define NB    4
#define KS    11
#define RAD   5
#define TH    16
#define TW    16
#define HALO  26                // TH + 2*RAD
#define SPITCH 27               // staging pitch (odd)
#define IPITCH 9                // interm pitch in u32 pairs (8 + 1 pad)
#define IPF   (HALO * IPITCH)   // 234 u32 per field
#define C1F   (0.01f * 0.01f)
#define C2F   (0.03f * 0.03f)

typedef _Float16 h2v __attribute__((ext_vector_type(2)));
typedef _Float16 h8  __attribute__((ext_vector_type(8)));

__device__ __forceinline__ void make_window(float* g) {
    float s = 0.f;
#pragma unroll
    for (int i = 0; i < KS; ++i) {
        float c = (float)(i - RAD);
        g[i] = expf(-(c * c) * (1.0f / 4.5f));  // 2*sigma^2 = 4.5
        s += g[i];
    }
    float inv = 1.0f / s;
#pragma unroll
    for (int i = 0; i < KS; ++i) g[i] *= inv;
}

__device__ __forceinline__ unsigned pk(float a, float b) {
    unsigned lo = __builtin_bit_cast(unsigned short, (_Float16)a);
    unsigned hi = __builtin_bit_cast(unsigned short, (_Float16)b);
    return lo | (hi << 16);
}

#define SSIM_ACC(MP, MT, E2, T2, PT) do {                                 \
    float _mps = (MP) * (MP), _mts = (MT) * (MT), _mpt = (MP) * (MT);     \
    float _num = (2.f * _mpt + C1F) * (2.f * ((PT) - _mpt) + C2F);        \
    float _den = (_mps + _mts + C1F) *                                    \
                 (((E2) - _mps) + ((T2) - _mts) + C2F);                   \
    ssim_sum += _num * __builtin_amdgcn_rcpf(_den);                       \
} while (0)

__global__ __launch_bounds__(256) void fused_ssim_kernel(
    const float* __restrict__ pred, const float* __restrict__ targ,
    float* __restrict__ partials) {
    __shared__ float sp[HALO * SPITCH];        // 2808 B
    __shared__ float st[HALO * SPITCH];        // 2808 B
    __shared__ unsigned interm[5 * IPF];       // 4680 B (2 fp16 cols / u32)
    __shared__ h8 ring4[KS * 128];             // 22528 B (px-pair x 4 fields)
    __shared__ unsigned ring1[KS * 128];       // 5632 B (px-pair pt)
    __shared__ float red[4];

    float g[KS];
    make_window(g);

    const int tid = threadIdx.x;
    const int tile = blockIdx.x;              // 0..143
    const int h0 = (tile / 12) * TH;
    const int w0 = (tile % 12) * TW;
    const int seg = blockIdx.y;               // 0: out 0..33, 1: out 34..63
    const int b   = blockIdx.z;

    const int d0 = seg ? 29 : 0;
    const int d1 = seg ? 68 : 38;             // inclusive; >63 = virtual zeros
    const int demit = seg ? 39 : 5;           // emit od = dd-5 when dd >= demit

    // zero ring (covers virtual planes < 0 for seg 0; harmless for seg 1)
    const h8 hz = {(_Float16)0, (_Float16)0, (_Float16)0, (_Float16)0,
                   (_Float16)0, (_Float16)0, (_Float16)0, (_Float16)0};
    for (int i = tid; i < KS * 128; i += 256) {
        ring4[i] = hz;
        ring1[i] = 0u;
    }

    const float* pb = pred + (size_t)b * VOL;
    const float* tb = targ + (size_t)b * VOL;

    float ssim_sum = 0.f;

#pragma unroll 1
    for (int dd = d0; dd <= d1; ++dd) {
        const int slot = dd % KS;
        if (dd < D_DIM) {
            // ---- S: stage 26x26 halo (zero-padded at edges) ----
            __syncthreads();   // ring read (prev D) done; also guards sp/st
            const float* pp = pb + dd * SLICE;
            const float* tt = tb + dd * SLICE;
            for (int i = tid; i < HALO * HALO; i += 256) {
                int y = i / HALO, x = i - y * HALO;
                int gh = h0 + y - RAD, gw = w0 + x - RAD;
                float pv = 0.f, tv = 0.f;
                if ((unsigned)gh < (unsigned)H_DIM && (unsigned)gw < (unsigned)W_DIM) {
                    int idx = gh * W_DIM + gw;
                    pv = pp[idx];
                    tv = tt[idx];
                }
                sp[y * SPITCH + x] = pv;
                st[y * SPITCH + x] = tv;
            }
            __syncthreads();
            // ---- W: blur along W, 2 cols/thread, 5 fields ----
            if (tid < 208) {
                const int row = tid >> 3;           // 0..25
                const int xp  = tid & 7;            // col pair 0..7
                float wp[12], wt[12];
#pragma unroll
                for (int k = 0; k < 12; ++k) {
                    wp[k] = sp[row * SPITCH + 2 * xp + k];
                    wt[k] = st[row * SPITCH + 2 * xp + k];
                }
                float s00 = 0.f, s01 = 0.f, s10 = 0.f, s11 = 0.f;
                float s20 = 0.f, s21 = 0.f, s30 = 0.f, s31 = 0.f;
                float s40 = 0.f, s41 = 0.f;
#pragma unroll
                for (int k = 0; k < KS; ++k) {
                    float gk = g[k];
                    float p0 = wp[k], t0 = wt[k];
                    float p1 = wp[k + 1], t1 = wt[k + 1];
                    s00 += gk * p0;      s01 += gk * p1;
                    s10 += gk * t0;      s11 += gk * t1;
                    s20 += gk * p0 * p0; s21 += gk * p1 * p1;
                    s30 += gk * t0 * t0; s31 += gk * t1 * t1;
                    s40 += gk * p0 * t0; s41 += gk * p1 * t1;
                }
                const int ib = row * IPITCH + xp;
                interm[0 * IPF + ib] = pk(s00, s01);
                interm[1 * IPF + ib] = pk(s10, s11);
                interm[2 * IPF + ib] = pk(s20, s21);
                interm[3 * IPF + ib] = pk(s30, s31);
                interm[4 * IPF + ib] = pk(s40, s41);
            }
            __syncthreads();
            // ---- H: blur along H, 2 cols/thread -> ring slot ----
            if (tid < 128) {
                const int y  = tid >> 3;            // 0..15
                const int xp = tid & 7;             // col pair
                float a00 = 0.f, a01 = 0.f, a10 = 0.f, a11 = 0.f;
                float a20 = 0.f, a21 = 0.f, a30 = 0.f, a31 = 0.f;
                float a40 = 0.f, a41 = 0.f;
#pragma unroll
                for (int k = 0; k < KS; ++k) {
                    float gk = g[k];
                    int rb = (y + k) * IPITCH + xp;
                    h2v v0 = __builtin_bit_cast(h2v, interm[0 * IPF + rb]);
                    h2v v1 = __builtin_bit_cast(h2v, interm[1 * IPF + rb]);
                    h2v v2 = __builtin_bit_cast(h2v, interm[2 * IPF + rb]);
                    h2v v3 = __builtin_bit_cast(h2v, interm[3 * IPF + rb]);
                    h2v v4 = __builtin_bit_cast(h2v, interm[4 * IPF + rb]);
                    a00 += gk * (float)v0[0]; a01 += gk * (float)v0[1];
                    a10 += gk * (float)v1[0]; a11 += gk * (float)v1[1];
                    a20 += gk * (float)v2[0]; a21 += gk * (float)v2[1];
                    a30 += gk * (float)v3[0]; a31 += gk * (float)v3[1];
                    a40 += gk * (float)v4[0]; a41 += gk * (float)v4[1];
                }
                h8 o;
                o[0] = (_Float16)a00; o[1] = (_Float16)a10;
                o[2] = (_Float16)a20; o[3] = (_Float16)a30;
                o[4] = (_Float16)a01; o[5] = (_Float16)a11;
                o[6] = (_Float16)a21; o[7] = (_Float16)a31;
                ring4[slot * 128 + tid] = o;
                ring1[slot * 128 + tid] = pk(a40, a41);
            }
        } else {
            // virtual zero plane (D tail, seg 1 only)
            __syncthreads();
            if (tid < 128) {
                ring4[slot * 128 + tid] = hz;
                ring1[slot * 128 + tid] = 0u;
            }
        }
        __syncthreads();
        // ---- D: dot ring with g, SSIM for output od = dd-5 ----
        if (dd >= demit && tid < 128) {
            const int sbase = (dd + 1) % KS;     // slot of plane od-5
            float mp0 = 0.f, mt0 = 0.f, e20 = 0.f, t20 = 0.f, pt0 = 0.f;
            float mp1 = 0.f, mt1 = 0.f, e21 = 0.f, t21 = 0.f, pt1 = 0.f;
#pragma unroll
            for (int j = 0; j < KS; ++j) {
                int s = sbase + j;
                s = (s >= KS) ? s - KS : s;
                h8 v = ring4[s * 128 + tid];
                h2v yv = __builtin_bit_cast(h2v, ring1[s * 128 + tid]);
                float gj = g[j];
                mp0 += gj * (float)v[0]; mt0 += gj * (float)v[1];
                e20 += gj * (float)v[2]; t20 += gj * (float)v[3];
                mp1 += gj * (float)v[4]; mt1 += gj * (float)v[5];
                e21 += gj * (float)v[6]; t21 += gj * (float)v[7];
                pt0 += gj * (float)yv[0]; pt1 += gj * (float)yv[1];
            }
            SSIM_ACC(mp0, mt0, e20, t20, pt0);
            SSIM_ACC(mp1, mt1, e21, t21, pt1);
        }
    }

    // ---- block reduction -> one partial per block ----
    float a = ssim_sum;
#pragma unroll
    for (int off = 32; off > 0; off >>= 1) a += __shfl_down(a, off, 64);
    int lane = tid & 63, wv = tid >> 6;
    if (lane == 0) red[wv] = a;
    __syncthreads();
    if (tid == 0) {
        int bid = (blockIdx.z * 2 + blockIdx.y) * 144 + blockIdx.x;
        partials[bid] = red[0] + red[1] + red[2] + red[3];
    }
}

// ---- finalize ----
__global__ __launch_bounds__(256) void finalize_kernel(
    const float* __restrict__ partials, int n, float* __restrict__ out) {
    double a = 0.0;
    for (int i = threadIdx.x; i < n; i += 256) a += (double)partials[i];
#pragma unroll
    for (int off = 32; off > 0; off >>= 1) a += __shfl_down(a, off, 64);
    __shared__ double red[4];
    int lane = threadIdx.x & 63, wv = threadIdx.x >> 6;
    if (lane == 0) red[wv] = a;
    __syncthreads();
    if (threadIdx.x == 0) {
        double s = red[0] + red[1] + red[2] + red[3];
        out[0] = (float)(1.0 - s / (double)((long long)NB * VOL));
    }
}

extern "C" void kernel_launch(void* const* d_in, const int* in_sizes, int n_in,
                              void* d_out, int out_size, void* d_ws, size_t ws_size,
                              hipStream_t stream) {
    const float* pred = (const float*)d_in[0];
    const float* targ = (const float*)d_in[1];
    float* out = (float*)d_out;
    float* partials = (float*)d_ws;           // 1152 floats

    fused_ssim_kernel<<<dim3(144, 2, NB), 256, 0, stream>>>(pred, targ, partials);
    finalize_kernel<<<1, 256, 0, stream>>>(partials, 144 * 2 * NB, out);
}